// Round 2
// baseline (334.192 us; speedup 1.0000x reference)
//
#include <hip/hip_runtime.h>

typedef __bf16 bf16_t;
typedef __attribute__((ext_vector_type(8))) __bf16 bf16x8;
typedef __attribute__((ext_vector_type(4))) __bf16 bf16x4;
typedef __attribute__((ext_vector_type(4))) float f32x4;

// async global->LDS, 16B per lane. LDS dest must be wave-uniform base + lane*16.
#define GLL16(gsrc, ldst)                                                                   \
  __builtin_amdgcn_global_load_lds(                                                         \
      (const __attribute__((address_space(1))) unsigned int*)(gsrc),                        \
      (__attribute__((address_space(3))) unsigned int*)(ldst), 16, 0, 0)

// ---------------- problem dims ----------------
#define BATCH 16
#define TT    2048
#define DD    512
#define FF    256
#define MTOT  (BATCH * TT)   // 32768

// ---------------- cast kernels ----------------
__global__ __launch_bounds__(256) void cast_x_kernel(const float* __restrict__ x,
                                                     bf16_t* __restrict__ xb, int n4) {
  int stride = gridDim.x * blockDim.x;
  for (int i = blockIdx.x * blockDim.x + threadIdx.x; i < n4; i += stride) {
    float4 v = ((const float4*)x)[i];
    bf16x4 o;
    o[0] = (bf16_t)v.x; o[1] = (bf16_t)v.y; o[2] = (bf16_t)v.z; o[3] = (bf16_t)v.w;
    ((bf16x4*)xb)[i] = o;
  }
}

// WqkvT[n][k] = Wqkv[k][n] (768x512), WoutT[n][k] = Wout[k][n] (512x256)
__global__ __launch_bounds__(256) void cast_w_kernel(const float* __restrict__ Wqkv,
                                                     const float* __restrict__ Wout,
                                                     bf16_t* __restrict__ WqkvT,
                                                     bf16_t* __restrict__ WoutT) {
  int t = blockIdx.x * blockDim.x + threadIdx.x;
  if (t < 768 * 512) {
    int n = t >> 9, k = t & 511;
    WqkvT[t] = (bf16_t)Wqkv[k * 768 + n];
  } else {
    int t2 = t - 768 * 512;
    if (t2 < 512 * 256) {
      int n = t2 >> 8, k = t2 & 255;
      WoutT[t2] = (bf16_t)Wout[k * 512 + n];
    }
  }
}

// ---------------- GEMM 1: X[32768,512] x WqkvT[768,512] -> Q,K row-major, V transposed ----
// 128x128 tile, BK=32, 256 threads (4 waves, 2x2), 16x16x32 bf16 MFMA.
// LDS tiles [128][32] bf16, chunk swizzle: chunk' = chunk ^ ((row>>1)&3)  (2-way max)
__global__ __launch_bounds__(256) void gemm_qkv_kernel(const bf16_t* __restrict__ A,
                                                       const bf16_t* __restrict__ Bt,
                                                       const float* __restrict__ bias,
                                                       bf16_t* __restrict__ Qo,
                                                       bf16_t* __restrict__ Ko,
                                                       bf16_t* __restrict__ Vt) {
  __shared__ __align__(16) bf16_t Al[2][128 * 32];
  __shared__ __align__(16) bf16_t Bl[2][128 * 32];
  const int tid = threadIdx.x;
  const int l = tid & 63, w = tid >> 6;
  const int g = l >> 4, r = l & 15;
  const int wm = w >> 1, wn = w & 1;
  const int m0 = blockIdx.y * 128;
  const int n0 = blockIdx.x * 128;
  const int lda = 512, ldb = 512;
  const bf16_t* Abase = A + (size_t)m0 * lda;
  const bf16_t* Bbase = Bt + (size_t)n0 * ldb;

  f32x4 acc[4][4] = {};

  auto stage = [&](int kt, int bufi) {
    const int k0 = kt * 32;
#pragma unroll
    for (int rnd = 0; rnd < 2; ++rnd) {
      int idx = rnd * 256 + tid;
      int row = idx >> 2, d = idx & 3;
      int sc = d ^ ((row >> 1) & 3);
      GLL16(Abase + row * lda + k0 + sc * 8, &Al[bufi][idx * 8]);
    }
#pragma unroll
    for (int rnd = 0; rnd < 2; ++rnd) {
      int idx = rnd * 256 + tid;
      int row = idx >> 2, d = idx & 3;
      int sc = d ^ ((row >> 1) & 3);
      GLL16(Bbase + row * ldb + k0 + sc * 8, &Bl[bufi][idx * 8]);
    }
  };

  stage(0, 0);
  __syncthreads();
  int buf = 0;
  const int NK = 512 / 32;
  for (int kt = 0; kt < NK; ++kt) {
    if (kt + 1 < NK) stage(kt + 1, buf ^ 1);
    bf16x8 af[4], bfr[4];
#pragma unroll
    for (int mi = 0; mi < 4; ++mi) {
      int row = wm * 64 + mi * 16 + r;
      int cc = g ^ ((row >> 1) & 3);
      af[mi] = *(const bf16x8*)&Al[buf][row * 32 + cc * 8];
    }
#pragma unroll
    for (int ni = 0; ni < 4; ++ni) {
      int row = wn * 64 + ni * 16 + r;
      int cc = g ^ ((row >> 1) & 3);
      bfr[ni] = *(const bf16x8*)&Bl[buf][row * 32 + cc * 8];
    }
#pragma unroll
    for (int mi = 0; mi < 4; ++mi)
#pragma unroll
      for (int ni = 0; ni < 4; ++ni)
        acc[mi][ni] = __builtin_amdgcn_mfma_f32_16x16x32_bf16(af[mi], bfr[ni], acc[mi][ni], 0, 0, 0);
    __syncthreads();
    buf ^= 1;
  }

  // epilogue: D[row=(l>>4)*4+i][col=l&15]; n-tile sel: 0,1->Q  2,3->K  4,5->V(transposed)
  const int qsel = n0 >> 8;
#pragma unroll
  for (int mi = 0; mi < 4; ++mi) {
    int row0 = m0 + wm * 64 + mi * 16 + g * 4;
#pragma unroll
    for (int ni = 0; ni < 4; ++ni) {
      int col = n0 + wn * 64 + ni * 16 + r;
      float bv = bias[col];
      int cl = col & 255;
      if (qsel == 2) {
        bf16x4 pk;
#pragma unroll
        for (int i = 0; i < 4; ++i) pk[i] = (bf16_t)(acc[mi][ni][i] + bv);
        int b = row0 >> 11, t0 = row0 & 2047;
        *(bf16x4*)&Vt[((size_t)(b * 256 + cl)) * 2048 + t0] = pk;
      } else {
        bf16_t* dst = (qsel == 0) ? Qo : Ko;
#pragma unroll
        for (int i = 0; i < 4; ++i)
          dst[(size_t)(row0 + i) * 256 + cl] = (bf16_t)(acc[mi][ni][i] + bv);
      }
    }
  }
}

// ---------------- flash attention ----------------
// grid (16 q-tiles, 16 batches), 512 threads = 8 waves, each wave owns 16 q rows.
// Swapped MFMAs: S^T = mfma(K, Q) (softmax state at q = lane&15),
//                ctx^T = mfma(V^T, P^T) (rescale lane-local, packed ctx stores).
__global__ __launch_bounds__(512, 2) void attn_kernel(const bf16_t* __restrict__ Q,
                                                      const bf16_t* __restrict__ K,
                                                      const bf16_t* __restrict__ Vt,
                                                      bf16_t* __restrict__ ctx) {
  __shared__ __align__(16) bf16_t Kl[64 * 256];   // [kv][f], 512B rows, chunk ^= row&7
  __shared__ __align__(16) bf16_t Vl[256 * 64];   // [f][kv], 128B rows, chunk ^= row&7
  __shared__ __align__(16) bf16_t Pl[8][16 * 72]; // per-wave P [q][kv], pad 72 (2-way max)
  const int tid = threadIdx.x;
  const int l = tid & 63, w = tid >> 6;
  const int g = l >> 4, r = l & 15;
  const int b = blockIdx.y;
  const int q0 = blockIdx.x * 128 + w * 16;
  const bf16_t* Kb = K + ((size_t)b * TT) * 256;
  const bf16_t* Vb = Vt + (size_t)b * 256 * TT;

  bf16x8 qf[8];
  const bf16_t* Qrow = Q + ((size_t)(b * TT) + q0 + r) * 256;
#pragma unroll
  for (int kf = 0; kf < 8; ++kf) qf[kf] = *(const bf16x8*)(Qrow + kf * 32 + g * 8);

  f32x4 cacc[16] = {};
  float m_run = -3.0e38f, l_run = 0.0f;

  for (int kv0 = 0; kv0 < TT; kv0 += 64) {
    __syncthreads();
#pragma unroll
    for (int rnd = 0; rnd < 4; ++rnd) {  // K tile: 64 rows x 32 chunks
      int idx = rnd * 512 + tid;
      int row = idx >> 5, d = idx & 31;
      int sc = d ^ (row & 7);
      GLL16(Kb + (size_t)(kv0 + row) * 256 + sc * 8, &Kl[idx * 8]);
    }
#pragma unroll
    for (int rnd = 0; rnd < 4; ++rnd) {  // V^T tile: 256 rows x 8 chunks
      int idx = rnd * 512 + tid;
      int row = idx >> 3, d = idx & 7;
      int sc = d ^ (row & 7);
      GLL16(Vb + (size_t)row * TT + kv0 + sc * 8, &Vl[idx * 8]);
    }
    __syncthreads();

    // S^T[kv][q] accumulation
    f32x4 st[4] = {};
#pragma unroll
    for (int kf = 0; kf < 8; ++kf) {
#pragma unroll
      for (int kvf = 0; kvf < 4; ++kvf) {
        int row = kvf * 16 + r;
        int c = kf * 4 + g;
        bf16x8 kfr = *(const bf16x8*)&Kl[row * 256 + ((c ^ (row & 7)) * 8)];
        st[kvf] = __builtin_amdgcn_mfma_f32_16x16x32_bf16(kfr, qf[kf], st[kvf], 0, 0, 0);
      }
    }

    // online softmax over this tile; per-lane state is for q = r
    float tmax = -3.0e38f;
    float s[4][4];
#pragma unroll
    for (int kvf = 0; kvf < 4; ++kvf)
#pragma unroll
      for (int i = 0; i < 4; ++i) {
        s[kvf][i] = st[kvf][i] * 0.0625f;
        tmax = fmaxf(tmax, s[kvf][i]);
      }
    tmax = fmaxf(tmax, __shfl_xor(tmax, 16));
    tmax = fmaxf(tmax, __shfl_xor(tmax, 32));
    float mnew = fmaxf(m_run, tmax);
    float alpha = __expf(m_run - mnew);
    float psum = 0.0f;
#pragma unroll
    for (int kvf = 0; kvf < 4; ++kvf) {
      bf16x4 pk;
#pragma unroll
      for (int i = 0; i < 4; ++i) {
        float p = __expf(s[kvf][i] - mnew);
        psum += p;
        pk[i] = (bf16_t)p;
      }
      *(bf16x4*)&Pl[w][r * 72 + kvf * 16 + g * 4] = pk;  // P[q=r][kv=kvf*16+4g..+3]
    }
    psum += __shfl_xor(psum, 16);
    psum += __shfl_xor(psum, 32);
    l_run = l_run * alpha + psum;
    m_run = mnew;
#pragma unroll
    for (int fc = 0; fc < 16; ++fc)
#pragma unroll
      for (int i = 0; i < 4; ++i) cacc[fc][i] *= alpha;

    // PV: ctx^T[f][q] += V^T x P^T (same-wave LDS round-trip for P, in-order DS pipe)
#pragma unroll
    for (int kk = 0; kk < 2; ++kk) {
      bf16x8 pf = *(const bf16x8*)&Pl[w][r * 72 + kk * 32 + g * 8];
#pragma unroll
      for (int fc = 0; fc < 16; ++fc) {
        int row = fc * 16 + r;
        int c = kk * 4 + g;
        bf16x8 vf = *(const bf16x8*)&Vl[row * 64 + ((c ^ (row & 7)) * 8)];
        cacc[fc] = __builtin_amdgcn_mfma_f32_16x16x32_bf16(vf, pf, cacc[fc], 0, 0, 0);
      }
    }
  }

  // epilogue: ctx[q][f], f = fc*16 + 4g + i, q = r (8B packed stores)
  float inv = 1.0f / l_run;
  bf16_t* crow = ctx + ((size_t)(b * TT) + q0 + r) * 256;
#pragma unroll
  for (int fc = 0; fc < 16; ++fc) {
    bf16x4 pk;
#pragma unroll
    for (int i = 0; i < 4; ++i) pk[i] = (bf16_t)(cacc[fc][i] * inv);
    *(bf16x4*)(crow + fc * 16 + g * 4) = pk;
  }
}

// ---------------- GEMM 2: ctx[32768,256] x WoutT[512,256] + bias + X -> out fp32 --------
__global__ __launch_bounds__(256) void gemm_out_kernel(const bf16_t* __restrict__ A,
                                                       const bf16_t* __restrict__ Bt,
                                                       const float* __restrict__ bias,
                                                       const float* __restrict__ X,
                                                       float* __restrict__ Out) {
  __shared__ __align__(16) bf16_t Al[2][128 * 32];
  __shared__ __align__(16) bf16_t Bl[2][128 * 32];
  const int tid = threadIdx.x;
  const int l = tid & 63, w = tid >> 6;
  const int g = l >> 4, r = l & 15;
  const int wm = w >> 1, wn = w & 1;
  const int m0 = blockIdx.y * 128;
  const int n0 = blockIdx.x * 128;
  const int lda = 256, ldb = 256;
  const bf16_t* Abase = A + (size_t)m0 * lda;
  const bf16_t* Bbase = Bt + (size_t)n0 * ldb;

  f32x4 acc[4][4] = {};

  auto stage = [&](int kt, int bufi) {
    const int k0 = kt * 32;
#pragma unroll
    for (int rnd = 0; rnd < 2; ++rnd) {
      int idx = rnd * 256 + tid;
      int row = idx >> 2, d = idx & 3;
      int sc = d ^ ((row >> 1) & 3);
      GLL16(Abase + row * lda + k0 + sc * 8, &Al[bufi][idx * 8]);
    }
#pragma unroll
    for (int rnd = 0; rnd < 2; ++rnd) {
      int idx = rnd * 256 + tid;
      int row = idx >> 2, d = idx & 3;
      int sc = d ^ ((row >> 1) & 3);
      GLL16(Bbase + row * ldb + k0 + sc * 8, &Bl[bufi][idx * 8]);
    }
  };

  stage(0, 0);
  __syncthreads();
  int buf = 0;
  const int NK = 256 / 32;
  for (int kt = 0; kt < NK; ++kt) {
    if (kt + 1 < NK) stage(kt + 1, buf ^ 1);
    bf16x8 af[4], bfr[4];
#pragma unroll
    for (int mi = 0; mi < 4; ++mi) {
      int row = wm * 64 + mi * 16 + r;
      int cc = g ^ ((row >> 1) & 3);
      af[mi] = *(const bf16x8*)&Al[buf][row * 32 + cc * 8];
    }
#pragma unroll
    for (int ni = 0; ni < 4; ++ni) {
      int row = wn * 64 + ni * 16 + r;
      int cc = g ^ ((row >> 1) & 3);
      bfr[ni] = *(const bf16x8*)&Bl[buf][row * 32 + cc * 8];
    }
#pragma unroll
    for (int mi = 0; mi < 4; ++mi)
#pragma unroll
      for (int ni = 0; ni < 4; ++ni)
        acc[mi][ni] = __builtin_amdgcn_mfma_f32_16x16x32_bf16(af[mi], bfr[ni], acc[mi][ni], 0, 0, 0);
    __syncthreads();
    buf ^= 1;
  }

#pragma unroll
  for (int mi = 0; mi < 4; ++mi) {
    int row0 = m0 + wm * 64 + mi * 16 + g * 4;
#pragma unroll
    for (int ni = 0; ni < 4; ++ni) {
      int col = n0 + wn * 64 + ni * 16 + r;
      float bv = bias[col];
#pragma unroll
      for (int i = 0; i < 4; ++i) {
        size_t off = (size_t)(row0 + i) * 512 + col;
        Out[off] = acc[mi][ni][i] + bv + X[off];
      }
    }
  }
}

// ---------------- launch ----------------
extern "C" void kernel_launch(void* const* d_in, const int* in_sizes, int n_in,
                              void* d_out, int out_size, void* d_ws, size_t ws_size,
                              hipStream_t stream) {
  const float* X    = (const float*)d_in[0];  // [16,2048,512]
  const float* Wqkv = (const float*)d_in[1];  // [1,512,768]
  const float* bqkv = (const float*)d_in[2];  // [768]
  const float* Wout = (const float*)d_in[3];  // [1,256,512]
  const float* bout = (const float*)d_in[4];  // [512]
  float* out = (float*)d_out;

  char* ws = (char*)d_ws;
  // layout (needs ~81 MB): Xbf 32M | WqkvT 768K | WoutT 256K | Q 16M | K 16M | Vt 16M
  bf16_t* Xbf   = (bf16_t*)ws;
  bf16_t* ctx   = Xbf;  // alias: Xbf dead after gemm_qkv
  bf16_t* WqkvT = (bf16_t*)(ws + 33554432);
  bf16_t* WoutT = (bf16_t*)(ws + 34340864);
  bf16_t* Qb    = (bf16_t*)(ws + 34603008);
  bf16_t* Kb    = (bf16_t*)(ws + 51380224);
  bf16_t* Vt    = (bf16_t*)(ws + 68157440);

  cast_x_kernel<<<2048, 256, 0, stream>>>(X, Xbf, (MTOT * DD) / 4);
  cast_w_kernel<<<2048, 256, 0, stream>>>(Wqkv, Wout, WqkvT, WoutT);
  gemm_qkv_kernel<<<dim3(6, 256), 256, 0, stream>>>(Xbf, WqkvT, bqkv, Qb, Kb, Vt);
  attn_kernel<<<dim3(16, 16), 512, 0, stream>>>(Qb, Kb, Vt, ctx);
  gemm_out_kernel<<<dim3(4, 256), 256, 0, stream>>>(ctx, WoutT, bout, X, out);
}

// Round 3
// 315.573 us; speedup vs baseline: 1.0590x; 1.0590x over previous
//
#include <hip/hip_runtime.h>

typedef __bf16 bf16_t;
typedef __attribute__((ext_vector_type(8))) __bf16 bf16x8;
typedef __attribute__((ext_vector_type(4))) __bf16 bf16x4;
typedef __attribute__((ext_vector_type(4))) float f32x4;

// async global->LDS, 16B per lane. LDS dest must be wave-uniform base + lane*16.
#define GLL16(gsrc, ldst)                                                                   \
  __builtin_amdgcn_global_load_lds(                                                         \
      (const __attribute__((address_space(1))) unsigned int*)(gsrc),                        \
      (__attribute__((address_space(3))) unsigned int*)(ldst), 16, 0, 0)

// ---------------- problem dims ----------------
#define BATCH 16
#define TT    2048
#define DD    512
#define FF    256
#define MTOT  (BATCH * TT)   // 32768

// ---------------- cast kernels ----------------
__global__ __launch_bounds__(256) void cast_x_kernel(const float* __restrict__ x,
                                                     bf16_t* __restrict__ xb, int n4) {
  int stride = gridDim.x * blockDim.x;
  for (int i = blockIdx.x * blockDim.x + threadIdx.x; i < n4; i += stride) {
    float4 v = ((const float4*)x)[i];
    bf16x4 o;
    o[0] = (bf16_t)v.x; o[1] = (bf16_t)v.y; o[2] = (bf16_t)v.z; o[3] = (bf16_t)v.w;
    ((bf16x4*)xb)[i] = o;
  }
}

// WqkvT[n][k] = Wqkv[k][n] (768x512), WoutT[n][k] = Wout[k][n] (512x256)
__global__ __launch_bounds__(256) void cast_w_kernel(const float* __restrict__ Wqkv,
                                                     const float* __restrict__ Wout,
                                                     bf16_t* __restrict__ WqkvT,
                                                     bf16_t* __restrict__ WoutT) {
  int t = blockIdx.x * blockDim.x + threadIdx.x;
  if (t < 768 * 512) {
    int n = t >> 9, k = t & 511;
    WqkvT[t] = (bf16_t)Wqkv[k * 768 + n];
  } else {
    int t2 = t - 768 * 512;
    if (t2 < 512 * 256) {
      int n = t2 >> 8, k = t2 & 255;
      WoutT[t2] = (bf16_t)Wout[k * 512 + n];
    }
  }
}

// ---------------- GEMM 1: X[32768,512] x WqkvT[768,512] -> Q,K row-major, V transposed ----
// 128x128 tile, BK=32, 256 threads (4 waves, 2x2), 16x16x32 bf16 MFMA.
// 1-D grid 1536, chunked XCD swizzle (192 wgs/XCD share A-panel + all of B in L2).
__global__ __launch_bounds__(256) void gemm_qkv_kernel(const bf16_t* __restrict__ A,
                                                       const bf16_t* __restrict__ Bt,
                                                       const float* __restrict__ bias,
                                                       bf16_t* __restrict__ Qo,
                                                       bf16_t* __restrict__ Ko,
                                                       bf16_t* __restrict__ Vt) {
  __shared__ __align__(16) bf16_t Al[2][128 * 32];
  __shared__ __align__(16) bf16_t Bl[2][128 * 32];
  const int tid = threadIdx.x;
  const int l = tid & 63, w = tid >> 6;
  const int g = l >> 4, r = l & 15;
  const int wm = w >> 1, wn = w & 1;
  const int lin = blockIdx.x;                       // 1536 blocks
  const int wid = (lin & 7) * 192 + (lin >> 3);     // bijective chunked XCD swizzle
  const int m0 = (wid / 6) * 128;
  const int n0 = (wid % 6) * 128;
  const int lda = 512, ldb = 512;
  const bf16_t* Abase = A + (size_t)m0 * lda;
  const bf16_t* Bbase = Bt + (size_t)n0 * ldb;

  f32x4 acc[4][4] = {};

  auto stage = [&](int kt, int bufi) {
    const int k0 = kt * 32;
#pragma unroll
    for (int rnd = 0; rnd < 2; ++rnd) {
      int idx = rnd * 256 + tid;
      int row = idx >> 2, d = idx & 3;
      int sc = d ^ ((row >> 1) & 3);
      GLL16(Abase + row * lda + k0 + sc * 8, &Al[bufi][idx * 8]);
    }
#pragma unroll
    for (int rnd = 0; rnd < 2; ++rnd) {
      int idx = rnd * 256 + tid;
      int row = idx >> 2, d = idx & 3;
      int sc = d ^ ((row >> 1) & 3);
      GLL16(Bbase + row * ldb + k0 + sc * 8, &Bl[bufi][idx * 8]);
    }
  };

  stage(0, 0);
  __syncthreads();
  int buf = 0;
  const int NK = 512 / 32;
  for (int kt = 0; kt < NK; ++kt) {
    if (kt + 1 < NK) stage(kt + 1, buf ^ 1);
    bf16x8 af[4], bfr[4];
#pragma unroll
    for (int mi = 0; mi < 4; ++mi) {
      int row = wm * 64 + mi * 16 + r;
      int cc = g ^ ((row >> 1) & 3);
      af[mi] = *(const bf16x8*)&Al[buf][row * 32 + cc * 8];
    }
#pragma unroll
    for (int ni = 0; ni < 4; ++ni) {
      int row = wn * 64 + ni * 16 + r;
      int cc = g ^ ((row >> 1) & 3);
      bfr[ni] = *(const bf16x8*)&Bl[buf][row * 32 + cc * 8];
    }
#pragma unroll
    for (int mi = 0; mi < 4; ++mi)
#pragma unroll
      for (int ni = 0; ni < 4; ++ni)
        acc[mi][ni] = __builtin_amdgcn_mfma_f32_16x16x32_bf16(af[mi], bfr[ni], acc[mi][ni], 0, 0, 0);
    __syncthreads();
    buf ^= 1;
  }

  // epilogue: D[row=(l>>4)*4+i][col=l&15]; n-tile sel: 0,1->Q  2,3->K  4,5->V(transposed)
  const int qsel = n0 >> 8;
#pragma unroll
  for (int mi = 0; mi < 4; ++mi) {
    int row0 = m0 + wm * 64 + mi * 16 + g * 4;
#pragma unroll
    for (int ni = 0; ni < 4; ++ni) {
      int col = n0 + wn * 64 + ni * 16 + r;
      float bv = bias[col];
      int cl = col & 255;
      if (qsel == 2) {
        bf16x4 pk;
#pragma unroll
        for (int i = 0; i < 4; ++i) pk[i] = (bf16_t)(acc[mi][ni][i] + bv);
        int b = row0 >> 11, t0 = row0 & 2047;
        *(bf16x4*)&Vt[((size_t)(b * 256 + cl)) * 2048 + t0] = pk;
      } else {
        bf16_t* dst = (qsel == 0) ? Qo : Ko;
#pragma unroll
        for (int i = 0; i < 4; ++i)
          dst[(size_t)(row0 + i) * 256 + cl] = (bf16_t)(acc[mi][ni][i] + bv);
      }
    }
  }
}

// ---------------- flash attention ----------------
// 256 blocks (XCD-chunk-swizzled: 2 batches per XCD -> K/V L2-resident),
// 512 threads = 8 waves, each wave owns 16 q rows.
// Double-buffered K/V staging (T3-min): issue next tile's global_load_lds before
// compute of current, one vmcnt(0)+barrier per tile. Defer-max (THR=8) skips the
// cacc rescale on tiles where the running max doesn't grow.
__global__ __launch_bounds__(512, 2) void attn_kernel(const bf16_t* __restrict__ Q,
                                                      const bf16_t* __restrict__ K,
                                                      const bf16_t* __restrict__ Vt,
                                                      bf16_t* __restrict__ ctx) {
  __shared__ __align__(16) bf16_t Kl[2][64 * 256];   // [kv][f], chunk ^= row&7 (32KB x2)
  __shared__ __align__(16) bf16_t Vl[2][256 * 64];   // [f][kv], chunk ^= row&7 (32KB x2)
  __shared__ __align__(16) bf16_t Pl[8][16 * 64];    // per-wave P [q][64], chunk ^= q&7 (16KB)
  const int tid = threadIdx.x;
  const int l = tid & 63, w = tid >> 6;
  const int g = l >> 4, r = l & 15;
  const int lin = blockIdx.x;                        // 256 blocks
  const int wid = (lin & 7) * 32 + (lin >> 3);       // chunked XCD swizzle
  const int b = wid >> 4;
  const int q0 = (wid & 15) * 128 + w * 16;
  const bf16_t* Kb = K + ((size_t)b * TT) * 256;
  const bf16_t* Vb = Vt + (size_t)b * 256 * TT;

  bf16x8 qf[8];
  const bf16_t* Qrow = Q + ((size_t)(b * TT) + q0 + r) * 256;
#pragma unroll
  for (int kf = 0; kf < 8; ++kf) qf[kf] = *(const bf16x8*)(Qrow + kf * 32 + g * 8);

  f32x4 cacc[16] = {};
  float m_run = -3.0e38f, l_run = 0.0f;

  auto stage = [&](int kv0, int bi) {
#pragma unroll
    for (int rnd = 0; rnd < 4; ++rnd) {  // K tile: 64 rows x 32 chunks
      int idx = rnd * 512 + tid;
      int row = idx >> 5, d = idx & 31;
      int sc = d ^ (row & 7);
      GLL16(Kb + (size_t)(kv0 + row) * 256 + sc * 8, &Kl[bi][idx * 8]);
    }
#pragma unroll
    for (int rnd = 0; rnd < 4; ++rnd) {  // V^T tile: 256 rows x 8 chunks
      int idx = rnd * 512 + tid;
      int row = idx >> 3, d = idx & 7;
      int sc = d ^ (row & 7);
      GLL16(Vb + (size_t)row * TT + kv0 + sc * 8, &Vl[bi][idx * 8]);
    }
  };

  stage(0, 0);
  __syncthreads();           // drains vmcnt: buf0 ready
  int buf = 0;

  for (int kv0 = 0; kv0 < TT; kv0 += 64) {
    if (kv0 + 64 < TT) stage(kv0 + 64, buf ^ 1);   // prefetch next tile (in flight under compute)

    // S^T[kv][q] accumulation from Kl[buf]
    f32x4 st[4] = {};
#pragma unroll
    for (int kf = 0; kf < 8; ++kf) {
#pragma unroll
      for (int kvf = 0; kvf < 4; ++kvf) {
        int row = kvf * 16 + r;
        int c = kf * 4 + g;
        bf16x8 kfr = *(const bf16x8*)&Kl[buf][row * 256 + ((c ^ (row & 7)) * 8)];
        st[kvf] = __builtin_amdgcn_mfma_f32_16x16x32_bf16(kfr, qf[kf], st[kvf], 0, 0, 0);
      }
    }

    // online softmax; per-lane state is for q = r (replicated over the 4 g-lanes)
    float tmax = -3.0e38f;
    float s[4][4];
#pragma unroll
    for (int kvf = 0; kvf < 4; ++kvf)
#pragma unroll
      for (int i = 0; i < 4; ++i) {
        s[kvf][i] = st[kvf][i] * 0.0625f;
        tmax = fmaxf(tmax, s[kvf][i]);
      }
    tmax = fmaxf(tmax, __shfl_xor(tmax, 16));
    tmax = fmaxf(tmax, __shfl_xor(tmax, 32));
    if (!__all(tmax - m_run <= 8.0f)) {            // defer-max: rescale only on real growth
      float mnew = fmaxf(m_run, tmax);
      float alpha = __expf(m_run - mnew);
      l_run *= alpha;
#pragma unroll
      for (int fc = 0; fc < 16; ++fc)
#pragma unroll
        for (int i = 0; i < 4; ++i) cacc[fc][i] *= alpha;
      m_run = mnew;
    }
    float psum = 0.0f;
#pragma unroll
    for (int kvf = 0; kvf < 4; ++kvf) {
      bf16x4 pk;
#pragma unroll
      for (int i = 0; i < 4; ++i) {
        float p = __expf(s[kvf][i] - m_run);       // bounded by e^8
        psum += p;
        pk[i] = (bf16_t)p;
      }
      // P[q=r][kv=kvf*16+4g..+3], row 128B, 16B-chunk XOR swizzle by q&7
      int widx = r * 64 + ((((kvf * 2 + (g >> 1)) ^ (r & 7)) << 3) | ((g & 1) * 4));
      *(bf16x4*)&Pl[w][widx] = pk;
    }
    psum += __shfl_xor(psum, 16);
    psum += __shfl_xor(psum, 32);
    l_run += psum;

    // PV: ctx^T[f][q] += V^T x P^T (per-wave P LDS round-trip)
#pragma unroll
    for (int kk = 0; kk < 2; ++kk) {
      bf16x8 pf = *(const bf16x8*)&Pl[w][r * 64 + (((kk * 4 + g) ^ (r & 7)) << 3)];
#pragma unroll
      for (int fc = 0; fc < 16; ++fc) {
        int row = fc * 16 + r;
        int c = kk * 4 + g;
        bf16x8 vf = *(const bf16x8*)&Vl[buf][row * 64 + ((c ^ (row & 7)) * 8)];
        cacc[fc] = __builtin_amdgcn_mfma_f32_16x16x32_bf16(vf, pf, cacc[fc], 0, 0, 0);
      }
    }

    __syncthreads();         // drains vmcnt(0): next tile staged; all waves done with buf
    buf ^= 1;
  }

  // epilogue: ctx[q][f], f = fc*16 + 4g + i, q = r (8B packed stores)
  float inv = 1.0f / l_run;
  bf16_t* crow = ctx + ((size_t)(b * TT) + q0 + r) * 256;
#pragma unroll
  for (int fc = 0; fc < 16; ++fc) {
    bf16x4 pk;
#pragma unroll
    for (int i = 0; i < 4; ++i) pk[i] = (bf16_t)(cacc[fc][i] * inv);
    *(bf16x4*)(crow + fc * 16 + g * 4) = pk;
  }
}

// ---------------- GEMM 2: ctx[32768,256] x WoutT[512,256] + bias + X -> out fp32 --------
__global__ __launch_bounds__(256) void gemm_out_kernel(const bf16_t* __restrict__ A,
                                                       const bf16_t* __restrict__ Bt,
                                                       const float* __restrict__ bias,
                                                       const float* __restrict__ X,
                                                       float* __restrict__ Out) {
  __shared__ __align__(16) bf16_t Al[2][128 * 32];
  __shared__ __align__(16) bf16_t Bl[2][128 * 32];
  const int tid = threadIdx.x;
  const int l = tid & 63, w = tid >> 6;
  const int g = l >> 4, r = l & 15;
  const int wm = w >> 1, wn = w & 1;
  const int lin = blockIdx.x;                       // 1024 blocks
  const int wid = (lin & 7) * 128 + (lin >> 3);     // chunked XCD swizzle
  const int m0 = (wid >> 2) * 128;
  const int n0 = (wid & 3) * 128;
  const int lda = 256, ldb = 256;
  const bf16_t* Abase = A + (size_t)m0 * lda;
  const bf16_t* Bbase = Bt + (size_t)n0 * ldb;

  f32x4 acc[4][4] = {};

  auto stage = [&](int kt, int bufi) {
    const int k0 = kt * 32;
#pragma unroll
    for (int rnd = 0; rnd < 2; ++rnd) {
      int idx = rnd * 256 + tid;
      int row = idx >> 2, d = idx & 3;
      int sc = d ^ ((row >> 1) & 3);
      GLL16(Abase + row * lda + k0 + sc * 8, &Al[bufi][idx * 8]);
    }
#pragma unroll
    for (int rnd = 0; rnd < 2; ++rnd) {
      int idx = rnd * 256 + tid;
      int row = idx >> 2, d = idx & 3;
      int sc = d ^ ((row >> 1) & 3);
      GLL16(Bbase + row * ldb + k0 + sc * 8, &Bl[bufi][idx * 8]);
    }
  };

  stage(0, 0);
  __syncthreads();
  int buf = 0;
  const int NK = 256 / 32;
  for (int kt = 0; kt < NK; ++kt) {
    if (kt + 1 < NK) stage(kt + 1, buf ^ 1);
    bf16x8 af[4], bfr[4];
#pragma unroll
    for (int mi = 0; mi < 4; ++mi) {
      int row = wm * 64 + mi * 16 + r;
      int cc = g ^ ((row >> 1) & 3);
      af[mi] = *(const bf16x8*)&Al[buf][row * 32 + cc * 8];
    }
#pragma unroll
    for (int ni = 0; ni < 4; ++ni) {
      int row = wn * 64 + ni * 16 + r;
      int cc = g ^ ((row >> 1) & 3);
      bfr[ni] = *(const bf16x8*)&Bl[buf][row * 32 + cc * 8];
    }
#pragma unroll
    for (int mi = 0; mi < 4; ++mi)
#pragma unroll
      for (int ni = 0; ni < 4; ++ni)
        acc[mi][ni] = __builtin_amdgcn_mfma_f32_16x16x32_bf16(af[mi], bfr[ni], acc[mi][ni], 0, 0, 0);
    __syncthreads();
    buf ^= 1;
  }

#pragma unroll
  for (int mi = 0; mi < 4; ++mi) {
    int row0 = m0 + wm * 64 + mi * 16 + g * 4;
#pragma unroll
    for (int ni = 0; ni < 4; ++ni) {
      int col = n0 + wn * 64 + ni * 16 + r;
      float bv = bias[col];
#pragma unroll
      for (int i = 0; i < 4; ++i) {
        size_t off = (size_t)(row0 + i) * 512 + col;
        Out[off] = acc[mi][ni][i] + bv + X[off];
      }
    }
  }
}

// ---------------- launch ----------------
extern "C" void kernel_launch(void* const* d_in, const int* in_sizes, int n_in,
                              void* d_out, int out_size, void* d_ws, size_t ws_size,
                              hipStream_t stream) {
  const float* X    = (const float*)d_in[0];  // [16,2048,512]
  const float* Wqkv = (const float*)d_in[1];  // [1,512,768]
  const float* bqkv = (const float*)d_in[2];  // [768]
  const float* Wout = (const float*)d_in[3];  // [1,256,512]
  const float* bout = (const float*)d_in[4];  // [512]
  float* out = (float*)d_out;

  char* ws = (char*)d_ws;
  // layout (needs ~81 MB): Xbf 32M | WqkvT 768K | WoutT 256K | Q 16M | K 16M | Vt 16M
  bf16_t* Xbf   = (bf16_t*)ws;
  bf16_t* ctx   = Xbf;  // alias: Xbf dead after gemm_qkv
  bf16_t* WqkvT = (bf16_t*)(ws + 33554432);
  bf16_t* WoutT = (bf16_t*)(ws + 34340864);
  bf16_t* Qb    = (bf16_t*)(ws + 34603008);
  bf16_t* Kb    = (bf16_t*)(ws + 51380224);
  bf16_t* Vt    = (bf16_t*)(ws + 68157440);

  cast_x_kernel<<<2048, 256, 0, stream>>>(X, Xbf, (MTOT * DD) / 4);
  cast_w_kernel<<<2048, 256, 0, stream>>>(Wqkv, Wout, WqkvT, WoutT);
  gemm_qkv_kernel<<<1536, 256, 0, stream>>>(Xbf, WqkvT, bqkv, Qb, Kb, Vt);
  attn_kernel<<<256, 512, 0, stream>>>(Qb, Kb, Vt, ctx);
  gemm_out_kernel<<<1024, 256, 0, stream>>>(ctx, WoutT, bout, X, out);
}